// Round 4
// baseline (186.693 us; speedup 1.0000x reference)
//
#include <hip/hip_runtime.h>

// Spatial transformer: affine grid-sample, reflect padding, bilinear.
// x: (B=32, C=3, H=512, W=512) fp32; p: (B,4) fp32 = [tx, ty, theta, scale].
//
// R7: R6 (channel-split, adaptive box, XCD swizzle) reached ~58us but pays the
// tile setup + per-pixel coord/weight math 3x (once per channel). Changes:
//  - one block = 32x32 tile x ALL 3 channels, sequential. Per-pixel idx +
//    4 bilinear weights computed ONCE, kept in VGPRs, reused for 3 channels
//    (box geometry is channel-invariant).
//  - double-buffered LDS (2 x 13.5KB = 26.9KB -> 5 blocks/CU) with T14
//    reg-staging: issue ch(i+1) global loads -> compute ch(i) -> vmcnt drain +
//    ds_write. HBM latency hides under the gather+store of the previous ch.
//  - pads (zero column at nw4, 64-word guard row at nrows) written once for
//    BOTH buffers: weight-0 x1/y1 taps always read finite LDS (R5/R6 logic).
//  - XCD-chunked swizzle kept (8192 = 8 x 1024, bijective).

#define B_ 32
#define C_ 3
#define H_ 512
#define W_ 512
#define TILE 32
#define LSTRIDE 60                      // up to 15 float4 per row
#define MAXROWS 55                      // 2*ext+3 <= 54.3 for ts<1
#define BUFW (MAXROWS * LSTRIDE + 64)   // 3364 words: 55 rows + guard row
// 2 buffers = 26,912 B -> 5 blocks/CU

typedef float f32x4 __attribute__((ext_vector_type(4)));

// reflect onto [0, 511] with the reference's half-pixel convention.
// Exact for size=512: /1024, floor, and the mod subtraction are exact, so this
// is bit-identical to the reference's floor/fmod/parity form.
__device__ __forceinline__ float reflect512(float coord) {
    const float c = fabsf(coord + 0.5f);
    const float m = c - floorf(c * (1.0f / 1024.0f)) * 1024.0f;   // c mod 1024
    const float t = 512.0f - fabsf(m - 512.0f);
    return fminf(fmaxf(t - 0.5f, 0.0f), 511.0f);
}

__global__ __launch_bounds__(256, 5)
void st_kernel(const float* __restrict__ x, const float* __restrict__ p,
               float* __restrict__ out) {
    __shared__ float smem[2 * BUFW];    // 26,912 B

    const int tid = threadIdx.x;

    // ---- XCD-chunked work swizzle (grid 8192 = 8 * 1024, bijective) ----
    const int bid = blockIdx.x;
    const int wid = (bid & 7) * 1024 + (bid >> 3);
    const int b   = wid >> 8;           // 0..31
    const int til = wid & 255;
    const int tlx = til & 15;
    const int tly = til >> 4;

    const float tx = p[b * 4 + 0];
    const float ty = p[b * 4 + 1];
    const float th = p[b * 4 + 2];
    const float ts = p[b * 4 + 3];
    const float cth = __cosf(th), sth = __sinf(th);   // th in [0,1): well-conditioned
    const float a  =  ts * cth;         // ix step per output col
    const float bb = -ts * sth;         // ix step per output row
    const float d  =  ts * sth;         // iy step per output col (e == a)

    // ---- block-uniform adaptive staging box (center of the 32x32 tile) ----
    const float xs_c = ((float)(tlx * TILE) + 16.0f) * (2.0f / W_) - 1.0f;
    const float ys_c = ((float)(tly * TILE) + 16.0f) * (2.0f / H_) - 1.0f;
    const float gxc = a * xs_c + bb * ys_c + tx;
    const float gyc = d * xs_c + a  * ys_c + ty;
    const float rcx = reflect512(((gxc + 1.0f) * W_ - 1.0f) * 0.5f);
    const float rcy = reflect512(((gyc + 1.0f) * H_ - 1.0f) * 0.5f);
    // per-pixel |delta| <= 15.5*(|a|+|bb|); reflect+clip are 1-Lipschitz.
    const float ext = 16.0f * (fabsf(a) + fabsf(bb)) + 3.0f;

    int bx0 = max((int)floorf(rcx - ext), 0) & ~3;          // 16B-aligned
    const int xhi = min((int)ceilf(rcx + ext) + 1, W_);     // +1: real x1 tap
    int nw4 = (xhi - bx0 + 3) >> 2;
    nw4 = min(min(nw4, 15), (W_ - bx0) >> 2);

    int by0 = max((int)floorf(rcy - ext), 0);
    const int yhi = min((int)ceilf(rcy + ext) + 1, H_);
    const int nrows = min(yhi - by0, MAXROWS);

    const size_t plane = (size_t)H_ * W_;
    const float* img = x + (size_t)b * C_ * plane;
    const size_t gbase = (size_t)by0 * W_ + bx0;
    const int c4 = tid & 15;            // float4 slot in row
    const int r0 = tid >> 4;            // 0..15

    // ---- stage ch0 direct into buf0; zero pads for BOTH buffers ----
    {
        const float* gp = img + gbase;
        for (int r = r0; r < nrows; r += 16)
            if (c4 < nw4)
                *reinterpret_cast<f32x4*>(&smem[r * LSTRIDE + c4 * 4]) =
                    *reinterpret_cast<const f32x4*>(gp + (size_t)r * W_ + c4 * 4);
        if (nw4 < 15)
            for (int r = r0; r < nrows; r += 16)
                if (c4 == nw4) {        // zero column after staged width
                    *reinterpret_cast<f32x4*>(&smem[r * LSTRIDE + c4 * 4]) = (f32x4)(0.0f);
                    *reinterpret_cast<f32x4*>(&smem[BUFW + r * LSTRIDE + c4 * 4]) = (f32x4)(0.0f);
                }
        if (tid < 16) {                 // 64-word zero guard row (y1 taps at row nrows)
            *reinterpret_cast<f32x4*>(&smem[nrows * LSTRIDE + tid * 4]) = (f32x4)(0.0f);
            *reinterpret_cast<f32x4*>(&smem[BUFW + nrows * LSTRIDE + tid * 4]) = (f32x4)(0.0f);
        }
    }

    // ---- per-pixel idx + weights, computed ONCE for all 3 channels ----
    const int lr   = tid >> 3;          // 0..31
    const int lc   = (tid & 7) * 4;     // 0,4,...,28
    const int row  = tly * TILE + lr;
    const int col0 = tlx * TILE + lc;

    const float ysn = ((float)row  + 0.5f) * (2.0f / H_) - 1.0f;
    const float xsn = ((float)col0 + 0.5f) * (2.0f / W_) - 1.0f;
    float ix = ((a * xsn + bb * ysn + tx + 1.0f) * W_ - 1.0f) * 0.5f;
    float iy = ((d * xsn + a  * ysn + ty + 1.0f) * H_ - 1.0f) * 0.5f;

    const int koff = by0 * LSTRIDE + bx0;
    int   idx4[4];
    float w00_[4], w01_[4], w10_[4], w11_[4];
    #pragma unroll
    for (int k = 0; k < 4; ++k) {
        const float rx  = reflect512(ix);
        const float ry  = reflect512(iy);
        const float x0f = floorf(rx);
        const float y0f = floorf(ry);
        const float fx  = rx - x0f;
        const float fy  = ry - y0f;
        const float ox  = 1.0f - fx;
        const float oy  = 1.0f - fy;
        w00_[k] = ox * oy; w01_[k] = fx * oy; w10_[k] = ox * fy; w11_[k] = fx * fy;
        idx4[k] = (int)y0f * LSTRIDE + (int)x0f - koff;
        ix += a;
        iy += d;
    }

    float* outp = out + (size_t)b * C_ * plane + (size_t)row * W_ + col0;

    // T14 reg-staging helpers (4 predicated float4 per thread covers 55 rows)
    f32x4 vr[4];
    auto load_regs = [&](int ch) {
        const float* gp = img + (size_t)ch * plane + gbase;
        #pragma unroll
        for (int i = 0; i < 4; ++i) {
            const int rr = min(r0 + i * 16, nrows - 1);   // in-bounds clamp
            vr[i] = (c4 < nw4)
                ? *reinterpret_cast<const f32x4*>(gp + (size_t)rr * W_ + c4 * 4)
                : (f32x4)(0.0f);
        }
    };
    auto write_regs = [&](float* base) {
        #pragma unroll
        for (int i = 0; i < 4; ++i) {
            const int r = r0 + i * 16;
            if (r < nrows && c4 < nw4)
                *reinterpret_cast<f32x4*>(base + r * LSTRIDE + c4 * 4) = vr[i];
        }
    };
    auto compute_store = [&](int ch, const float* base) {
        float acc[4];
        #pragma unroll
        for (int k = 0; k < 4; ++k) {
            const float* s = base + idx4[k];
            acc[k] = s[0] * w00_[k] + s[1] * w01_[k]
                   + s[LSTRIDE] * w10_[k] + s[LSTRIDE + 1] * w11_[k];
        }
        const f32x4 v = {acc[0], acc[1], acc[2], acc[3]};
        __builtin_nontemporal_store(v, reinterpret_cast<f32x4*>(outp + (size_t)ch * plane));
    };

    __syncthreads();                    // buf0 (ch0) ready

    load_regs(1);                       // issue ch1 loads (latency hides below)
    compute_store(0, smem);             // gather ch0 from buf0
    write_regs(smem + BUFW);            // drain + ds_write ch1 -> buf1
    __syncthreads();                    // buf1 ready; all buf0 reads done

    load_regs(2);                       // issue ch2 loads
    compute_store(1, smem + BUFW);      // gather ch1 from buf1
    write_regs(smem);                   // ds_write ch2 -> buf0
    __syncthreads();                    // buf0 (ch2) ready

    compute_store(2, smem);             // gather ch2
}

extern "C" void kernel_launch(void* const* d_in, const int* in_sizes, int n_in,
                              void* d_out, int out_size, void* d_ws, size_t ws_size,
                              hipStream_t stream) {
    const float* x = (const float*)d_in[0];
    const float* p = (const float*)d_in[1];
    float* out = (float*)d_out;

    dim3 block(256, 1, 1);
    dim3 grid((W_ / TILE) * (H_ / TILE) * B_, 1, 1);    // 8192
    st_kernel<<<grid, block, 0, stream>>>(x, p, out);
}

// Round 5
// 179.717 us; speedup vs baseline: 1.0388x; 1.0388x over previous
//
#include <hip/hip_runtime.h>

// Spatial transformer: affine grid-sample, reflect padding, bilinear.
// x: (B=32, C=3, H=512, W=512) fp32; p: (B,4) fp32 = [tx, ty, theta, scale].
//
// R8: R6 (channel-split) == R7 (fused, pipelined) == 60us -> VALU not the wall;
// R7's VGPR bloat (idx+16 weights+16 stage regs) likely crossed the 64-VGPR
// occupancy cliff and gave back its fusion gains. This round: fusion with
// register discipline.
//  - one block = 32x32 tile x 3 channels; per-px state = idx4[4]+fx[4]+fy[4]
//    (12 regs); bilinear weights recomputed per channel (5 VALU/px, cheap).
//  - single 13.5KB LDS buffer, serial ch loop, 5 barriers; VGPR <= 64 =>
//    8 blocks/CU (32 waves, 100% occ) -- what R7 lost.
//  - staging: 4 unconditional clamped loads batched (no per-iter vmcnt
//    round trips), predicated ds_writes; pads written once, persist across ch.
//  - ch(k+1) loads issued BEFORE the barrier: the barrier's forced vmcnt(0)
//    drain covers their HBM latency.
//  - normal stores (A/B vs nontemporal: the 6.5TB/s fill uses normal).

#define B_ 32
#define C_ 3
#define H_ 512
#define W_ 512
#define TILE 32
#define LSTRIDE 60                      // 60 words/row; 28 mod 32 decorrelates banks
#define MAXROWS 55
#define SMEMW (MAXROWS * LSTRIDE + 64)  // 3364 words = 13,456 B -> 8 blocks/CU

typedef float f32x4 __attribute__((ext_vector_type(4)));

// reflect onto [0, 511], half-pixel convention; exact for pow2 size (bit-
// identical to the reference's floor/fmod/parity form).
__device__ __forceinline__ float reflect512(float coord) {
    const float c = fabsf(coord + 0.5f);
    const float m = c - floorf(c * (1.0f / 1024.0f)) * 1024.0f;   // c mod 1024
    const float t = 512.0f - fabsf(m - 512.0f);
    return fminf(fmaxf(t - 0.5f, 0.0f), 511.0f);
}

__global__ __launch_bounds__(256, 8)
void st_kernel(const float* __restrict__ x, const float* __restrict__ p,
               float* __restrict__ out) {
    __shared__ float smem[SMEMW];

    const int tid = threadIdx.x;

    // ---- XCD-chunked work swizzle (grid 8192 = 8 * 1024, bijective) ----
    const int bid = blockIdx.x;
    const int wid = (bid & 7) * 1024 + (bid >> 3);
    const int b   = wid >> 8;           // 0..31
    const int til = wid & 255;
    const int tlx = til & 15;
    const int tly = til >> 4;

    const float tx = p[b * 4 + 0];
    const float ty = p[b * 4 + 1];
    const float th = p[b * 4 + 2];
    const float ts = p[b * 4 + 3];
    const float cth = __cosf(th), sth = __sinf(th);
    const float a  =  ts * cth;         // ix step per output col
    const float bb = -ts * sth;         // ix step per output row
    const float d  =  ts * sth;         // iy step per output col (e == a)

    // ---- block-uniform adaptive staging box ----
    const float xs_c = ((float)(tlx * TILE) + 16.0f) * (2.0f / W_) - 1.0f;
    const float ys_c = ((float)(tly * TILE) + 16.0f) * (2.0f / H_) - 1.0f;
    const float gxc = a * xs_c + bb * ys_c + tx;
    const float gyc = d * xs_c + a  * ys_c + ty;
    const float rcx = reflect512(((gxc + 1.0f) * W_ - 1.0f) * 0.5f);
    const float rcy = reflect512(((gyc + 1.0f) * H_ - 1.0f) * 0.5f);
    const float ext = 16.0f * (fabsf(a) + fabsf(bb)) + 3.0f;   // 1-Lipschitz bound

    int bx0 = max((int)floorf(rcx - ext), 0) & ~3;             // 16B-aligned
    const int xhi = min((int)ceilf(rcx + ext) + 1, W_);        // +1: real x1 tap
    int nw4 = (xhi - bx0 + 3) >> 2;
    nw4 = min(min(nw4, 15), (W_ - bx0) >> 2);

    int by0 = max((int)floorf(rcy - ext), 0);
    const int yhi = min((int)ceilf(rcy + ext) + 1, H_);
    const int nrows = min(yhi - by0, MAXROWS);

    const size_t plane = (size_t)H_ * W_;
    const float* img = x + (size_t)b * C_ * plane;
    const int c4 = tid & 15;            // float4 slot in row (0..15)
    const int r0 = tid >> 4;            // 0..15
    // clamped (always-valid) load address components: loads unconditional,
    // writes predicated -> loads batch into one vmcnt group.
    const int ccl = min(c4, max(nw4 - 1, 0)) * 4;
    const float* gp0 = img + (size_t)by0 * W_ + bx0;

    f32x4 vr[4];
    #pragma unroll
    for (int i = 0; i < 4; ++i) {       // issue ch0 loads up front
        const int rr = min(r0 + i * 16, nrows - 1);
        vr[i] = *reinterpret_cast<const f32x4*>(gp0 + (size_t)rr * W_ + ccl);
    }

    // ---- per-px state (overlaps ch0 load latency): idx + fx + fy only ----
    const int lr   = tid >> 3;          // 0..31
    const int lc   = (tid & 7) * 4;     // 0,4,...,28
    const int row  = tly * TILE + lr;
    const int col0 = tlx * TILE + lc;

    const float ysn = ((float)row  + 0.5f) * (2.0f / H_) - 1.0f;
    const float xsn = ((float)col0 + 0.5f) * (2.0f / W_) - 1.0f;
    float ix = ((a * xsn + bb * ysn + tx + 1.0f) * W_ - 1.0f) * 0.5f;
    float iy = ((d * xsn + a  * ysn + ty + 1.0f) * H_ - 1.0f) * 0.5f;

    const int koff = by0 * LSTRIDE + bx0;
    int   idx4[4];
    float fx_[4], fy_[4];
    #pragma unroll
    for (int k = 0; k < 4; ++k) {
        const float rx  = reflect512(ix);
        const float ry  = reflect512(iy);
        const float x0f = floorf(rx);
        const float y0f = floorf(ry);
        fx_[k] = rx - x0f;
        fy_[k] = ry - y0f;
        idx4[k] = (int)y0f * LSTRIDE + (int)x0f - koff;
        ix += a;
        iy += d;
    }

    // ---- write ch0 + pads (pads persist across channels) ----
    #pragma unroll
    for (int i = 0; i < 4; ++i) {
        const int r = r0 + i * 16;
        if (r < nrows && c4 < nw4)
            *reinterpret_cast<f32x4*>(&smem[r * LSTRIDE + c4 * 4]) = vr[i];
    }
    if (nw4 < 15) {
        #pragma unroll
        for (int i = 0; i < 4; ++i) {   // zero column after staged width
            const int r = r0 + i * 16;
            if (r < nrows && c4 == nw4)
                *reinterpret_cast<f32x4*>(&smem[r * LSTRIDE + c4 * 4]) = (f32x4)(0.0f);
        }
    }
    if (tid < 16)                       // zero guard row (y1 taps at row nrows)
        *reinterpret_cast<f32x4*>(&smem[nrows * LSTRIDE + tid * 4]) = (f32x4)(0.0f);

    float* outp = out + (size_t)b * C_ * plane + (size_t)row * W_ + col0;

    #pragma unroll
    for (int ch = 0; ch < C_; ++ch) {
        __syncthreads();                // staged data (+pads) visible

        // gather + store this channel; weights recomputed (5 VALU/px)
        float acc[4];
        #pragma unroll
        for (int k = 0; k < 4; ++k) {
            const float fx = fx_[k], fy = fy_[k];
            const float ox = 1.0f - fx, oy = 1.0f - fy;
            const float* s = &smem[idx4[k]];
            acc[k] = s[0] * (ox * oy) + s[1] * (fx * oy)
                   + s[LSTRIDE] * (ox * fy) + s[LSTRIDE + 1] * (fx * fy);
        }
        const f32x4 v = {acc[0], acc[1], acc[2], acc[3]};
        *reinterpret_cast<f32x4*>(outp + (size_t)ch * plane) = v;

        if (ch < C_ - 1) {
            // issue next channel's loads NOW: the following barrier's forced
            // vmcnt(0) drain covers their HBM latency.
            const float* gp = img + (size_t)(ch + 1) * plane
                                  + (size_t)by0 * W_ + bx0;
            #pragma unroll
            for (int i = 0; i < 4; ++i) {
                const int rr = min(r0 + i * 16, nrows - 1);
                vr[i] = *reinterpret_cast<const f32x4*>(gp + (size_t)rr * W_ + ccl);
            }
            __syncthreads();            // all reads of buffer done -> may overwrite
            #pragma unroll
            for (int i = 0; i < 4; ++i) {
                const int r = r0 + i * 16;
                if (r < nrows && c4 < nw4)
                    *reinterpret_cast<f32x4*>(&smem[r * LSTRIDE + c4 * 4]) = vr[i];
            }
        }
    }
}

extern "C" void kernel_launch(void* const* d_in, const int* in_sizes, int n_in,
                              void* d_out, int out_size, void* d_ws, size_t ws_size,
                              hipStream_t stream) {
    const float* x = (const float*)d_in[0];
    const float* p = (const float*)d_in[1];
    float* out = (float*)d_out;

    dim3 block(256, 1, 1);
    dim3 grid((W_ / TILE) * (H_ / TILE) * B_, 1, 1);    // 8192
    st_kernel<<<grid, block, 0, stream>>>(x, p, out);
}